// Round 2
// baseline (150.826 us; speedup 1.0000x reference)
//
#include <hip/hip_runtime.h>
#include <hip/hip_bf16.h>

#define G_ 8
#define GIN_ 256
#define GOUT_ 256
#define NROWS_ 8192
#define LDX_ 2048   // = G_*GIN_ = row stride of x and out

typedef __attribute__((ext_vector_type(4))) float f32x4;
typedef __attribute__((ext_vector_type(8))) short bf16x8;

// LDS-only barrier: stores/loads in flight stay in flight (no vmcnt drain).
__device__ __forceinline__ void lds_barrier() {
    asm volatile("s_waitcnt lgkmcnt(0)\n\ts_barrier" ::: "memory");
}

// ---------------------------------------------------------------------------
// Prep: W [G][GIN][GOUT] f32  ->  Wt [G][GOUT][GIN] bf16 (transposed+converted)
// Grid: 128 blocks x 256 threads. LDS-tiled transpose: coalesced both ways.
// ---------------------------------------------------------------------------
__global__ __launch_bounds__(256) void wprep_kernel(const float* __restrict__ W,
                                                    __hip_bfloat16* __restrict__ Wt) {
    __shared__ float tile[64][65];   // +1 pad: conflict-free transposed read
    const int bid = blockIdx.x;
    const int g  = bid >> 4;
    const int ot = (bid >> 2) & 3;   // o-tile (64 wide)
    const int it = bid & 3;          // i-tile (64 wide)
    const float* Wg = W + g * GIN_ * GOUT_;
    __hip_bfloat16* Wtg = Wt + g * GIN_ * GOUT_;
    const int lane_o = threadIdx.x & 63;
    const int sub    = threadIdx.x >> 6;   // 0..3
#pragma unroll
    for (int r = 0; r < 16; ++r) {
        int i = r * 4 + sub;
        tile[i][lane_o] = Wg[(it * 64 + i) * GOUT_ + ot * 64 + lane_o];
    }
    __syncthreads();
#pragma unroll
    for (int r = 0; r < 16; ++r) {
        int o = r * 4 + sub;
        Wtg[(ot * 64 + o) * GIN_ + it * 64 + lane_o] = __float2bfloat16(tile[lane_o][o]);
    }
}

// ---------------------------------------------------------------------------
// Main fused kernel — ONE SLAB PER BLOCK for maximum block-level parallelism.
//  R1 evidence: 512-block / 4-slab-serialized version left every pipe ~80%
//  idle (MfmaUtil 7%, VALU 15%, Occ 30%, HBM 33%) — latency-bound lockstep
//  with nothing queued behind the 2 resident blocks/CU. Restructure:
//    Block = 256 threads (4 waves) covering 32 rows x 128 cols of one group.
//    Grid  = 8 g x 2 col-halves x 256 row-slabs = 4096 blocks (~16/CU queued)
//  Per block: issue x loads (HBM) -> issue B loads (L2-hot Wt) -> cvt ->
//  ds_write -> ONE barrier -> 8x(2 ds_read_b128 + 4 MFMA) -> epilogue.
//  Blocks are independent: staggered phases fill each other's stalls.
//  Cost: x slab read by 2 blocks (col-halves) — second read L2/L3-absorbed
//  (pair dispatched back-to-back, bid ±8).
//  LDS: single 16 KB slab, row stride 512 B, 16B-granule XOR swizzle
//  (granule ^ (row&7)) — identical layout/swizzle to the verified R0 kernel.
// ---------------------------------------------------------------------------
__global__ __launch_bounds__(256, 4) void gkan_kernel(const float* __restrict__ x,
                                                      const __hip_bfloat16* __restrict__ Wt,
                                                      const float* __restrict__ bias,
                                                      const float* __restrict__ pc,
                                                      const float* __restrict__ qc,
                                                      float* __restrict__ out) {
    __shared__ __align__(16) __hip_bfloat16 As[32 * 256];   // 16 KB, single buffer

    const int bid    = blockIdx.x;
    const int g      = bid & 7;
    const int ch     = (bid >> 3) & 1;   // col-half within group
    const int mblock = bid >> 4;         // 0..255
    const int row0   = mblock * 32;

    const int t    = threadIdx.x;
    const int wave = t >> 6;             // 0..3 -> cols [ch*128 + wave*32, +32)
    const int lane = t & 63;
    const int lm   = lane & 15;
    const int quad = lane >> 4;
    const int colbase = ch * 128 + wave * 32;   // within group

    // ---- issue x slab loads FIRST (longest latency: HBM) ----
    // thread owns 32 consecutive f32 of one slab row
    const int sr = t >> 3;               // 0..31  slab row
    const int su = t & 7;                // 0..7   128B unit within row
    const float* xs = x + (size_t)(row0 + sr) * LDX_ + g * GIN_ + su * 32;
    f32x4 st[8];
#pragma unroll
    for (int j = 0; j < 8; ++j)
        st[j] = *(const f32x4*)(xs + j * 4);

    // ---- B: register-resident, wave's 32 cols x K=256 (issued after x:
    //      consuming x needs only vmcnt(16), so B stays in flight) ----
    bf16x8 Breg[2][8];
    {
        const __hip_bfloat16* Wg = Wt + (size_t)g * (GIN_ * GOUT_)
                                      + (size_t)colbase * GIN_;
#pragma unroll
        for (int nt = 0; nt < 2; ++nt)
#pragma unroll
            for (int c = 0; c < 8; ++c)
                Breg[nt][c] = *(const bf16x8*)(Wg + (size_t)(nt * 16 + lm) * GIN_
                                                  + c * 32 + quad * 8);
    }

    // ---- per-lane constants ----
    const float p0 = pc[g * 4 + 0], p1 = pc[g * 4 + 1];
    const float p2 = pc[g * 4 + 2], p3 = pc[g * 4 + 3];
    const float q0 = qc[g * 3 + 0], q1 = qc[g * 3 + 1], q2 = qc[g * 3 + 2];
    float bb[2];
#pragma unroll
    for (int nt = 0; nt < 2; ++nt)
        bb[nt] = bias[g * GOUT_ + colbase + nt * 16 + lm];

    // ---- convert + swizzled LDS write (waits on x loads only) ----
    {
        __hip_bfloat16* rowp = &As[sr * 256];
#pragma unroll
        for (int k = 0; k < 4; ++k) {
            union { __hip_bfloat16 h[8]; bf16x8 v; } cv;
            const f32x4 a = st[2 * k], b = st[2 * k + 1];
            cv.h[0] = __float2bfloat16(a.x); cv.h[1] = __float2bfloat16(a.y);
            cv.h[2] = __float2bfloat16(a.z); cv.h[3] = __float2bfloat16(a.w);
            cv.h[4] = __float2bfloat16(b.x); cv.h[5] = __float2bfloat16(b.y);
            cv.h[6] = __float2bfloat16(b.z); cv.h[7] = __float2bfloat16(b.w);
            *(bf16x8*)(rowp + (((4 * su + k) ^ (sr & 7)) * 8)) = cv.v;
        }
    }
    lds_barrier();

    // ---- MFMA: 8 K-chunks x (2 mt x 2 nt) ----
    f32x4 acc[2][2] = {};
#pragma unroll
    for (int c = 0; c < 8; ++c) {
        bf16x8 af[2];
#pragma unroll
        for (int mt = 0; mt < 2; ++mt) {
            const int gh = (c * 4 + quad) ^ (lm & 7);
            af[mt] = *(const bf16x8*)(As + (mt * 16 + lm) * 256 + gh * 8);
        }
#pragma unroll
        for (int mt = 0; mt < 2; ++mt)
#pragma unroll
            for (int nt = 0; nt < 2; ++nt)
                acc[mt][nt] = __builtin_amdgcn_mfma_f32_16x16x32_bf16(
                    af[mt], Breg[nt][c], acc[mt][nt], 0, 0, 0);
    }

    // ---- epilogue: bias + rational, coalesced stores ----
#pragma unroll
    for (int nt = 0; nt < 2; ++nt) {
        const int col = g * GOUT_ + colbase + nt * 16 + lm;
#pragma unroll
        for (int mt = 0; mt < 2; ++mt)
#pragma unroll
            for (int r = 0; r < 4; ++r) {
                const int row = row0 + mt * 16 + quad * 4 + r;
                const float y   = acc[mt][nt][r] + bb[nt];
                const float num = p0 + y * (p1 + y * (p2 + y * p3));
                const float den = 1.0f + fabsf(y * (q0 + y * (q1 + y * q2)));
                out[(size_t)row * LDX_ + col] = num * __builtin_amdgcn_rcpf(den);
            }
    }
}

extern "C" void kernel_launch(void* const* d_in, const int* in_sizes, int n_in,
                              void* d_out, int out_size, void* d_ws, size_t ws_size,
                              hipStream_t stream) {
    const float* x = (const float*)d_in[0];
    const float* W = (const float*)d_in[1];
    const float* b = (const float*)d_in[2];
    const float* p = (const float*)d_in[3];
    const float* q = (const float*)d_in[4];
    float* out = (float*)d_out;

    __hip_bfloat16* Wt = (__hip_bfloat16*)d_ws;   // 1 MiB bf16 transposed W

    wprep_kernel<<<128, 256, 0, stream>>>(W, Wt);
    gkan_kernel<<<4096, 256, 0, stream>>>(x, Wt, b, p, q, out);
}

// Round 4
// 133.282 us; speedup vs baseline: 1.1316x; 1.1316x over previous
//
#include <hip/hip_runtime.h>
#include <hip/hip_bf16.h>

#define G_ 8
#define GIN_ 256
#define GOUT_ 256
#define NROWS_ 8192
#define LDX_ 2048   // = G_*GIN_ = row stride of x and out

typedef __attribute__((ext_vector_type(4))) float f32x4;
typedef __attribute__((ext_vector_type(8))) short bf16x8;

// LDS-only barrier: no vmcnt(0) drain (global ops stay in flight).
__device__ __forceinline__ void lds_barrier() {
    asm volatile("s_waitcnt lgkmcnt(0)\n\ts_barrier" ::: "memory");
}

// ---------------------------------------------------------------------------
// Prep: W [G][GIN=k 256][GOUT=col 256] f32 -> WtB fragment-tiled bf16:
//   granule(g, c, cb, c16, quad) = W[g][k = c*32+quad*8 .. +8][col = cb*16+c16]
//   element offset = g*65536 + (c*16+cb)*512 + c16*32 + quad*8
// So a wave's B-frag load (16 cols x 4 quads x 16B) is ONE contiguous 1 KB.
// Grid: 128 blocks (8 g x 4 ktile x 4 coltile) x 256 thr, LDS-tiled.
// ---------------------------------------------------------------------------
__global__ __launch_bounds__(256) void wprep_kernel(const float* __restrict__ W,
                                                    __hip_bfloat16* __restrict__ Wt) {
    __shared__ float tile[64][65];   // +1 pad
    const int bid = blockIdx.x;
    const int g  = bid >> 4;
    const int kt = (bid >> 2) & 3;   // k-tile (64 wide)
    const int ct = bid & 3;          // col-tile (64 wide)
    const float* Wg = W + g * (GIN_ * GOUT_);
    __hip_bfloat16* Wo = Wt + (size_t)g * (GIN_ * GOUT_);
    const int lane_o = threadIdx.x & 63;   // col within tile
    const int sub    = threadIdx.x >> 6;   // 0..3
#pragma unroll
    for (int r = 0; r < 16; ++r) {
        int i = r * 4 + sub;               // k within tile
        tile[i][lane_o] = Wg[(kt * 64 + i) * GOUT_ + ct * 64 + lane_o];
    }
    __syncthreads();
    const int col = threadIdx.x & 63;
    const int kgb = threadIdx.x >> 6;      // 0..3
#pragma unroll
    for (int h = 0; h < 2; ++h) {
        const int kg    = kgb + h * 4;     // 0..7: granule-of-8k in 64-k tile
        const int kglob = kt * 64 + kg * 8;
        const int c     = kglob >> 5;      // k-chunk 0..7
        const int quad  = (kglob >> 3) & 3;
        const int colg  = ct * 64 + col;
        const int cb    = colg >> 4;
        const int c16   = colg & 15;
        union { __hip_bfloat16 hh[8]; bf16x8 v; } cv;
#pragma unroll
        for (int j = 0; j < 8; ++j)
            cv.hh[j] = __float2bfloat16(tile[kg * 8 + j][col]);
        *(bf16x8*)(Wo + (size_t)(c * 16 + cb) * 512 + c16 * 32 + quad * 8) = cv.v;
    }
}

// ---------------------------------------------------------------------------
// Main fused kernel — OCCUPANCY RESTRUCTURE (target 8 waves/SIMD).
//  R0-R2 evidence: both structures capped at ~16 waves/CU by the 64-VGPR
//  register-resident B (total ~110 regs/thread -> 4 waves/SIMD), all pipes
//  <=15% busy -> latency-bound. Fix: regs <= 64 so 8 waves/SIMD co-reside.
//   - Block 512 thr (8 waves), tile 32 rows x FULL 256 cols (x read ONCE).
//   - B: streamed per K-chunk from L2 (Wt[g] 128 KB, XCD-pinned by g=bid&7)
//     via 2x global_load_dwordx4/wave/chunk into TRANSIENT regs. wprep's
//     fragment-tiled layout makes each frag load contiguous 1 KB/wave.
//   - A: x slab (32r x 256k) cvt'd f32->bf16 into LDS ONCE, single buffer,
//     ONE barrier total. Chunk-contiguous layout: block (c, rblk) = 1 KB
//     contiguous; frag ds_read_b128 covers exactly that 1 KB -> uniform
//     banks by construction (R0's row-strided layout caused 1.31M confl).
//   - p/q/bias loaded AFTER the K-loop (9 fewer live regs in-loop).
//   - Rolled K-loop: minimal transients; latency hidden by occupancy.
// Grid: 8 g x 256 rowblocks = 2048 blocks; ~8 queued/CU, 4 resident.
// ---------------------------------------------------------------------------
__global__ __launch_bounds__(512, 8) void gkan_kernel(const float* __restrict__ x,
                                                      const __hip_bfloat16* __restrict__ Wt,
                                                      const float* __restrict__ bias,
                                                      const float* __restrict__ pc,
                                                      const float* __restrict__ qc,
                                                      float* __restrict__ out) {
    __shared__ __align__(16) __hip_bfloat16 As[8192];   // 16 KB: 16 x 1KB chunk-blocks

    const int bid  = blockIdx.x;
    const int g    = bid & 7;
    const int row0 = (bid >> 3) * 32;

    const int t    = threadIdx.x;
    const int wave = t >> 6;             // 0..7 -> cols [wave*32, +32)
    const int lane = t & 63;
    const int lm   = lane & 15;
    const int q    = lane >> 4;

    // ---- x slab loads: thread owns granules su and su+16 of one row ----
    const int row = t >> 4;              // 0..31
    const int su  = t & 15;              // 0..15
    const float* xs = x + (size_t)(row0 + row) * LDX_ + g * GIN_ + su * 8;
    f32x4 a0 = *(const f32x4*)(xs);
    f32x4 a1 = *(const f32x4*)(xs + 4);
    f32x4 b0 = *(const f32x4*)(xs + 128);
    f32x4 b1 = *(const f32x4*)(xs + 132);

    // ---- stage to LDS, chunk-contiguous + XOR slot swizzle ----
    // element addr(granule c,quad of row) = (c*2 + row/16)*512 + (row&15)*32
    //                                       + ((quad ^ (row&3))*8)
    {
        const int rblk = row >> 4, r16 = row & 15, rx = row & 3;
        const int c0 = su >> 2, quad = su & 3;
        const int slot = (quad ^ rx) * 8 + r16 * 32;
        union { __hip_bfloat16 hh[8]; bf16x8 v; } ca, cb;
        ca.hh[0] = __float2bfloat16(a0.x); ca.hh[1] = __float2bfloat16(a0.y);
        ca.hh[2] = __float2bfloat16(a0.z); ca.hh[3] = __float2bfloat16(a0.w);
        ca.hh[4] = __float2bfloat16(a1.x); ca.hh[5] = __float2bfloat16(a1.y);
        ca.hh[6] = __float2bfloat16(a1.z); ca.hh[7] = __float2bfloat16(a1.w);
        cb.hh[0] = __float2bfloat16(b0.x); cb.hh[1] = __float2bfloat16(b0.y);
        cb.hh[2] = __float2bfloat16(b0.z); cb.hh[3] = __float2bfloat16(b0.w);
        cb.hh[4] = __float2bfloat16(b1.x); cb.hh[5] = __float2bfloat16(b1.y);
        cb.hh[6] = __float2bfloat16(b1.z); cb.hh[7] = __float2bfloat16(b1.w);
        *(bf16x8*)(As + (c0 * 2 + rblk) * 512 + slot)       = ca.v;
        *(bf16x8*)(As + ((4 + c0) * 2 + rblk) * 512 + slot) = cb.v;
    }
    lds_barrier();

    // ---- K-loop: per chunk, 2 B-frags from L2 + 2 A-frags from LDS + 4 MFMA
    f32x4 acc[2][2] = {};
    const __hip_bfloat16* bp = Wt + (size_t)g * (GIN_ * GOUT_)
                                  + (wave * 2) * 512 + lm * 32 + q * 8;
    const __hip_bfloat16* ap = As + lm * 32 + ((q ^ (lm & 3)) * 8);
#pragma unroll 1
    for (int c = 0; c < 8; ++c) {
        const bf16x8 bf0 = *(const bf16x8*)(bp);         // nt=0
        const bf16x8 bf1 = *(const bf16x8*)(bp + 512);   // nt=1
        const bf16x8 af0 = *(const bf16x8*)(ap);         // mt=0
        const bf16x8 af1 = *(const bf16x8*)(ap + 512);   // mt=1
        acc[0][0] = __builtin_amdgcn_mfma_f32_16x16x32_bf16(af0, bf0, acc[0][0], 0, 0, 0);
        acc[0][1] = __builtin_amdgcn_mfma_f32_16x16x32_bf16(af0, bf1, acc[0][1], 0, 0, 0);
        acc[1][0] = __builtin_amdgcn_mfma_f32_16x16x32_bf16(af1, bf0, acc[1][0], 0, 0, 0);
        acc[1][1] = __builtin_amdgcn_mfma_f32_16x16x32_bf16(af1, bf1, acc[1][1], 0, 0, 0);
        bp += 16 * 512;    // next k-chunk (16 col-blocks ahead)
        ap += 2 * 512;     // next k-chunk (2 row-blocks ahead)
    }

    // ---- epilogue consts loaded HERE (not live during the loop) ----
    const float p0 = pc[g * 4 + 0], p1 = pc[g * 4 + 1];
    const float p2 = pc[g * 4 + 2], p3 = pc[g * 4 + 3];
    const float q0 = qc[g * 3 + 0], q1 = qc[g * 3 + 1], q2 = qc[g * 3 + 2];
    float bb[2];
#pragma unroll
    for (int nt = 0; nt < 2; ++nt)
        bb[nt] = bias[g * GOUT_ + wave * 32 + nt * 16 + lm];

    // ---- epilogue: bias + rational, coalesced stores ----
#pragma unroll
    for (int nt = 0; nt < 2; ++nt) {
        const int col = g * GOUT_ + wave * 32 + nt * 16 + lm;
#pragma unroll
        for (int mt = 0; mt < 2; ++mt)
#pragma unroll
            for (int r = 0; r < 4; ++r) {
                const int row_o = row0 + mt * 16 + q * 4 + r;
                const float y   = acc[mt][nt][r] + bb[nt];
                const float num = p0 + y * (p1 + y * (p2 + y * p3));
                const float den = 1.0f + fabsf(y * (q0 + y * (q1 + y * q2)));
                out[(size_t)row_o * LDX_ + col] = num * __builtin_amdgcn_rcpf(den);
            }
    }
}

extern "C" void kernel_launch(void* const* d_in, const int* in_sizes, int n_in,
                              void* d_out, int out_size, void* d_ws, size_t ws_size,
                              hipStream_t stream) {
    const float* x = (const float*)d_in[0];
    const float* W = (const float*)d_in[1];
    const float* b = (const float*)d_in[2];
    const float* p = (const float*)d_in[3];
    const float* q = (const float*)d_in[4];
    float* out = (float*)d_out;

    __hip_bfloat16* Wt = (__hip_bfloat16*)d_ws;   // 1 MiB fragment-tiled bf16 W

    wprep_kernel<<<128, 256, 0, stream>>>(W, Wt);
    gkan_kernel<<<2048, 512, 0, stream>>>(x, Wt, b, p, q, out);
}